// Round 10
// baseline (94.130 us; speedup 1.0000x reference)
//
#include <hip/hip_runtime.h>
#include <math.h>

// ThermostatNN: B independent 40-step rollouts of a 2->64->1 MLP plant +
// hysteresis thermostat. One thread per batch element.
//
// R10: kill the per-lane array instead of fighting the allocator.
// R4-R9 post-mortem: any long-lived per-lane array (c[64]) gets parked in
// AGPRs by the allocator under every structure tried (virtual pins, physical
// pins, launch bounds), costing ~190 v_accvgpr_read/mov per step. R9's full
// asm also broke bit-exactness (absmax 8.0). New structure:
//  - NO per-lane arrays. c[j] = fmaf(aux, r1[j], b1[j]) is recomputed each
//    step from broadcast LDS weights -- same inputs every step => bitwise
//    the SAME value as precomputing it (restores absmax 0.0), at +1 fma/unit.
//  - Packed fp32: v_pk_fma_f32 / v_pk_max_f32 via __builtin_elementwise_fma/
//    max on float2 halve the elementwise issue count (rounding per half is
//    IEEE fma/max, bit-identical to scalar).
//  - Weight loads keep R7's proven un-hoistable inline-asm ds_read_b128
//    (absmax was 0.0 with that mechanism), with the four arrays pair-
//    interleaved in LDS: Q1={a_e,a_o,r1_e,r1_o}, Q2={b1_e,b1_o,w2_e,w2_o};
//    one chunk = 8 loads = 8 hidden units. Broadcast (all lanes same addr),
//    conflict-free.
//  - acc chain stays SCALAR serial ascending-j (the bit-exactness anchor).
//
// NUMERICS (do not touch): serial single-accumulator dot in ascending-j
// order, expf-based stable sigmoid, explicitly rounded updates. One rounding
// flip in a hysteresis comparison diverges a trajectory by O(100).

#define LHID 64
#define NSTEPS 40

typedef __attribute__((ext_vector_type(4))) float f32x4;
typedef __attribute__((ext_vector_type(2))) float f32x2;

__global__ __launch_bounds__(256, 2) void thermostat_kernel(
    const float* __restrict__ x_init,  // (B,4): step, isOn, temp, aux
    const float* __restrict__ W1,      // (2,64) row-major
    const float* __restrict__ b1,      // (64)
    const float* __restrict__ W2,      // (64,1)
    const float* __restrict__ b2,      // (1)
    float* __restrict__ out,           // (40,B)
    int B)
{
    // LDS: per pair p (units 2p,2p+1), 8 floats at byte offset 32p:
    //   [0:4)  Q1 = { a[2p], a[2p+1], r1[2p], r1[2p+1] }
    //   [4:8)  Q2 = { b1[2p], b1[2p+1], w2[2p], w2[2p+1] }
    __shared__ __align__(16) float lds_w[8 * 32];

    int tid = threadIdx.x;
    if (tid < 32) {
        int p = tid;
        float4 q1 = { W1[2*p], W1[2*p+1], W1[LHID + 2*p], W1[LHID + 2*p+1] };
        float4 q2 = { b1[2*p], b1[2*p+1], W2[2*p], W2[2*p+1] };
        *reinterpret_cast<float4*>(&lds_w[8*p])     = q1;
        *reinterpret_cast<float4*>(&lds_w[8*p + 4]) = q2;
    }
    __syncthreads();

    int b = blockIdx.x * blockDim.x + tid;
    if (b >= B) return;

    float4 st = reinterpret_cast<const float4*>(x_init)[b];
    float step0 = st.x;
    float isOn  = st.y;
    float temp  = st.z;
    float aux   = st.w;
    float bias2 = b2[0];

    int n_active = (int)fminf(fmaxf((float)NSTEPS - step0, 0.0f), (float)NSTEPS);

    unsigned lbase = (unsigned)(uintptr_t)(void*)lds_w;
    float* po = out + b;

    // 8 loads per chunk: 4 Q1 quads + 4 Q2 quads covering 8 hidden units.
    // asm volatile => structurally un-hoistable (R7-proven, absmax 0.0).
#define LOAD_CHUNK(O0,O1,O2,O3,P0,P1,P2,P3)                                    \
    asm volatile("ds_read_b128 %0, %8 offset:" #O0 "\n\t"                      \
                 "ds_read_b128 %1, %8 offset:" #O1 "\n\t"                      \
                 "ds_read_b128 %2, %8 offset:" #O2 "\n\t"                      \
                 "ds_read_b128 %3, %8 offset:" #O3 "\n\t"                      \
                 "ds_read_b128 %4, %8 offset:" #P0 "\n\t"                      \
                 "ds_read_b128 %5, %8 offset:" #P1 "\n\t"                      \
                 "ds_read_b128 %6, %8 offset:" #P2 "\n\t"                      \
                 "ds_read_b128 %7, %8 offset:" #P3 "\n\t"                      \
                 "s_waitcnt lgkmcnt(0)"                                        \
                 : "=&v"(q10), "=&v"(q11), "=&v"(q12), "=&v"(q13),             \
                   "=&v"(q20), "=&v"(q21), "=&v"(q22), "=&v"(q23)              \
                 : "v"(lbase))

    // One pair (2 hidden units): 3 packed ops + 2 scalar serial fmacs.
    // c2 = fma(aux, r1, b1) per-step == precomputed c bitwise (same inputs).
#define PAIR(Q1, Q2)                                                           \
    {                                                                          \
        f32x2 a2 = __builtin_shufflevector((Q1), (Q1), 0, 1);                  \
        f32x2 r2 = __builtin_shufflevector((Q1), (Q1), 2, 3);                  \
        f32x2 bb = __builtin_shufflevector((Q2), (Q2), 0, 1);                  \
        f32x2 ww = __builtin_shufflevector((Q2), (Q2), 2, 3);                  \
        f32x2 c2 = __builtin_elementwise_fma(aux2, r2, bb);                    \
        f32x2 h2 = __builtin_elementwise_fma(t2, a2, c2);                      \
        h2 = __builtin_elementwise_max(h2, zero2);                             \
        acc = fmaf(h2.x, ww.x, acc);                                           \
        acc = fmaf(h2.y, ww.y, acc);                                           \
    }

#define CHUNK_MATH() PAIR(q10, q20) PAIR(q11, q21) PAIR(q12, q22) PAIR(q13, q23)

#pragma unroll 1
    for (int t = 0; t < NSTEPS; ++t) {
        float acc = 0.0f;
        f32x2 t2    = { temp, temp };
        f32x2 aux2  = { aux, aux };
        f32x2 zero2 = { 0.0f, 0.0f };
        {
            f32x4 q10,q11,q12,q13,q20,q21,q22,q23;
            LOAD_CHUNK(0,32,64,96, 16,48,80,112);
            CHUNK_MATH();
        }
        {
            f32x4 q10,q11,q12,q13,q20,q21,q22,q23;
            LOAD_CHUNK(128,160,192,224, 144,176,208,240);
            CHUNK_MATH();
        }
        {
            f32x4 q10,q11,q12,q13,q20,q21,q22,q23;
            LOAD_CHUNK(256,288,320,352, 272,304,336,368);
            CHUNK_MATH();
        }
        {
            f32x4 q10,q11,q12,q13,q20,q21,q22,q23;
            LOAD_CHUNK(384,416,448,480, 400,432,464,496);
            CHUNK_MATH();
        }
        {
            f32x4 q10,q11,q12,q13,q20,q21,q22,q23;
            LOAD_CHUNK(512,544,576,608, 528,560,592,624);
            CHUNK_MATH();
        }
        {
            f32x4 q10,q11,q12,q13,q20,q21,q22,q23;
            LOAD_CHUNK(640,672,704,736, 656,688,720,752);
            CHUNK_MATH();
        }
        {
            f32x4 q10,q11,q12,q13,q20,q21,q22,q23;
            LOAD_CHUNK(768,800,832,864, 784,816,848,880);
            CHUNK_MATH();
        }
        {
            f32x4 q10,q11,q12,q13,q20,q21,q22,q23;
            LOAD_CHUNK(896,928,960,992, 912,944,976,1008);
            CHUNK_MATH();
        }

        float x = __fadd_rn(acc, bias2);

        // stable sigmoid, single exact division (bitwise == two-branch form)
        float e = expf(-fabsf(x));
        float num = (x >= 0.0f) ? 1.0f : e;
        float s = num / (1.0f + e);

        // plant = s*10 - 5 ; dtemp = plant*10
        float plant = __fsub_rn(__fmul_rn(s, 10.0f), 5.0f);
        float dtemp = __fmul_rn(plant, 10.0f);

        float tn_off = __fadd_rn(temp, dtemp);
        float tn_on  = __fadd_rn(tn_off, 5.0f);

        bool off = (isOn <= 0.5f);
        float temp_new = off ? tn_off : tn_on;
        float isOn_new;
        if (off) isOn_new = (temp_new <= 66.0f) ? 1.0f : isOn;
        else     isOn_new = (temp_new <= 78.0f) ? isOn : 0.0f;

        if (t < n_active) {
            temp = temp_new;
            isOn = isOn_new;
        }

        *po = temp;
        po += B;
    }
#undef LOAD_CHUNK
#undef PAIR
#undef CHUNK_MATH
}

extern "C" void kernel_launch(void* const* d_in, const int* in_sizes, int n_in,
                              void* d_out, int out_size, void* d_ws, size_t ws_size,
                              hipStream_t stream) {
    const float* x_init = (const float*)d_in[0];
    const float* W1     = (const float*)d_in[1];
    const float* b1     = (const float*)d_in[2];
    const float* W2     = (const float*)d_in[3];
    const float* b2     = (const float*)d_in[4];
    float* out = (float*)d_out;

    int B = in_sizes[0] / 4;
    int threads = 256;
    int blocks = (B + threads - 1) / threads;
    thermostat_kernel<<<blocks, threads, 0, stream>>>(x_init, W1, b1, W2, b2, out, B);
}

// Round 11
// 89.907 us; speedup vs baseline: 1.0470x; 1.0470x over previous
//
#include <hip/hip_runtime.h>
#include <math.h>

// ThermostatNN: B independent 40-step rollouts of a 2->64->1 MLP plant +
// hysteresis thermostat. One thread per batch element.
//
// R11 = R10's no-per-lane-array core (which killed the AGPR tax: VGPR=32,
// absmax 0.0) with its two diseases fixed:
//  1. STALLS: R10 drained lgkmcnt to 0 eight times per step (VALUBusy 62%).
//     Now: 16 groups x 4 broadcast ds_read_b128, issue-ahead of 3 groups,
//     counted s_waitcnt lgkmcnt(12) per group (tail 8/4/0). The wait asm
//     takes the group's quads as "+v" operands, so the math is data-
//     dependent on the WAIT itself (no rule-18 hoisting hazard).
//  2. CODEGEN: R10's 32-VGPR allocation forced mass moves. Groups of 4
//     units with quads {a|r1|b1|w2} mean pk operands are the aligned
//     halves (.xy/.zw) of b128 destinations -> zero shuffle cost. Peak
//     live ~100 VGPR; __launch_bounds__(256,4) caps at 128 -> 4 waves/SIMD
//     (exactly what the grid supplies).
// Math per 4 units: 2 pk_fma (c = aux*r1+b1, recomputed per step == bitwise
// identical to precomputing) + 2 pk_fma (h) + 2 pk_max (relu) + 4 SERIAL
// scalar fmacs (the bit-exactness anchor) = 10 VALU. ~195 VALU/step total.
//
// NUMERICS (do not touch): serial single-accumulator dot in ascending-j
// order, expf-based stable sigmoid, explicitly rounded updates. v_pk_fma_f32
// halves are IEEE fma == fmaf. absmax == 0.0 in R1-R8/R10; one flipped
// hysteresis comparison diverges a trajectory by O(100).

#define LHID 64
#define NSTEPS 40

typedef __attribute__((ext_vector_type(4))) float f32x4;
typedef __attribute__((ext_vector_type(2))) float f32x2;

static __device__ __forceinline__ f32x2 lo2(f32x4 q) { return __builtin_shufflevector(q, q, 0, 1); }
static __device__ __forceinline__ f32x2 hi2(f32x4 q) { return __builtin_shufflevector(q, q, 2, 3); }

__global__ __launch_bounds__(256, 4) void thermostat_kernel(
    const float* __restrict__ x_init,  // (B,4): step, isOn, temp, aux
    const float* __restrict__ W1,      // (2,64) row-major
    const float* __restrict__ b1,      // (64)
    const float* __restrict__ W2,      // (64,1)
    const float* __restrict__ b2,      // (1)
    float* __restrict__ out,           // (40,B)
    int B)
{
    // LDS: group g (hidden units 4g..4g+3) at byte 64g:
    //   +0 QA=a[4g..], +16 QR=r1[4g..], +32 QB=b1[4g..], +48 QW=w2[4g..]
    __shared__ __align__(16) float lds_w[256];

    int tid = threadIdx.x;
    if (tid < LHID) {
        int g = tid >> 2, k = tid & 3;
        lds_w[16*g +      k] = W1[tid];         // a  = W1 row 0
        lds_w[16*g +  4 + k] = W1[LHID + tid];  // r1 = W1 row 1
        lds_w[16*g +  8 + k] = b1[tid];
        lds_w[16*g + 12 + k] = W2[tid];
    }
    __syncthreads();

    int b = blockIdx.x * blockDim.x + tid;
    if (b >= B) return;

    float4 st = reinterpret_cast<const float4*>(x_init)[b];
    float step0 = st.x;
    float isOn  = st.y;
    float temp  = st.z;
    float aux   = st.w;
    float bias2 = b2[0];

    int n_active = (int)fminf(fmaxf((float)NSTEPS - step0, 0.0f), (float)NSTEPS);

    unsigned lbase = (unsigned)(uintptr_t)(void*)lds_w;
    float* po = out + b;

    // ---- macros -------------------------------------------------------------
#define GDECL(g) f32x4 qa##g, qr##g, qb##g, qw##g;

#define ISSUE(g, O0, O1, O2, O3)                                               \
    asm volatile("ds_read_b128 %0, %4 offset:" #O0 "\n\t"                      \
                 "ds_read_b128 %1, %4 offset:" #O1 "\n\t"                      \
                 "ds_read_b128 %2, %4 offset:" #O2 "\n\t"                      \
                 "ds_read_b128 %3, %4 offset:" #O3                             \
                 : "=&v"(qa##g), "=&v"(qr##g), "=&v"(qb##g), "=&v"(qw##g)      \
                 : "v"(lbase))

#define WAITG(g, N)                                                            \
    asm volatile("s_waitcnt lgkmcnt(" #N ")"                                   \
                 : "+v"(qa##g), "+v"(qr##g), "+v"(qb##g), "+v"(qw##g))

#define MATH(g)                                                                \
    {                                                                          \
        f32x2 c01 = __builtin_elementwise_fma(aux2, lo2(qr##g), lo2(qb##g));   \
        f32x2 c23 = __builtin_elementwise_fma(aux2, hi2(qr##g), hi2(qb##g));   \
        f32x2 h01 = __builtin_elementwise_fma(t2, lo2(qa##g), c01);            \
        f32x2 h23 = __builtin_elementwise_fma(t2, hi2(qa##g), c23);            \
        h01 = __builtin_elementwise_max(h01, zero2);                           \
        h23 = __builtin_elementwise_max(h23, zero2);                           \
        acc = fmaf(h01.x, qw##g.x, acc);                                       \
        acc = fmaf(h01.y, qw##g.y, acc);                                       \
        acc = fmaf(h23.x, qw##g.z, acc);                                       \
        acc = fmaf(h23.y, qw##g.w, acc);                                       \
    }

#pragma unroll 1
    for (int t = 0; t < NSTEPS; ++t) {
        float acc = 0.0f;
        f32x2 t2    = { temp, temp };
        f32x2 aux2  = { aux, aux };
        f32x2 zero2 = { 0.0f, 0.0f };

        GDECL(0)  GDECL(1)  GDECL(2)  GDECL(3)
        GDECL(4)  GDECL(5)  GDECL(6)  GDECL(7)
        GDECL(8)  GDECL(9)  GDECL(10) GDECL(11)
        GDECL(12) GDECL(13) GDECL(14) GDECL(15)

        ISSUE(0, 0, 16, 32, 48);
        ISSUE(1, 64, 80, 96, 112);
        ISSUE(2, 128, 144, 160, 176);
        ISSUE(3, 192, 208, 224, 240);   WAITG(0, 12);  MATH(0);
        ISSUE(4, 256, 272, 288, 304);   WAITG(1, 12);  MATH(1);
        ISSUE(5, 320, 336, 352, 368);   WAITG(2, 12);  MATH(2);
        ISSUE(6, 384, 400, 416, 432);   WAITG(3, 12);  MATH(3);
        ISSUE(7, 448, 464, 480, 496);   WAITG(4, 12);  MATH(4);
        ISSUE(8, 512, 528, 544, 560);   WAITG(5, 12);  MATH(5);
        ISSUE(9, 576, 592, 608, 624);   WAITG(6, 12);  MATH(6);
        ISSUE(10, 640, 656, 672, 688);  WAITG(7, 12);  MATH(7);
        ISSUE(11, 704, 720, 736, 752);  WAITG(8, 12);  MATH(8);
        ISSUE(12, 768, 784, 800, 816);  WAITG(9, 12);  MATH(9);
        ISSUE(13, 832, 848, 864, 880);  WAITG(10, 12); MATH(10);
        ISSUE(14, 896, 912, 928, 944);  WAITG(11, 12); MATH(11);
        ISSUE(15, 960, 976, 992, 1008); WAITG(12, 12); MATH(12);
        WAITG(13, 8);  MATH(13);
        WAITG(14, 4);  MATH(14);
        WAITG(15, 0);  MATH(15);

        float x = __fadd_rn(acc, bias2);

        // stable sigmoid, single exact division (bitwise == two-branch form)
        float e = expf(-fabsf(x));
        float num = (x >= 0.0f) ? 1.0f : e;
        float s = num / (1.0f + e);

        // plant = s*10 - 5 ; dtemp = plant*10
        float plant = __fsub_rn(__fmul_rn(s, 10.0f), 5.0f);
        float dtemp = __fmul_rn(plant, 10.0f);

        float tn_off = __fadd_rn(temp, dtemp);
        float tn_on  = __fadd_rn(tn_off, 5.0f);

        bool off = (isOn <= 0.5f);
        float temp_new = off ? tn_off : tn_on;
        float isOn_new;
        if (off) isOn_new = (temp_new <= 66.0f) ? 1.0f : isOn;
        else     isOn_new = (temp_new <= 78.0f) ? isOn : 0.0f;

        if (t < n_active) {
            temp = temp_new;
            isOn = isOn_new;
        }

        *po = temp;
        po += B;
    }
#undef GDECL
#undef ISSUE
#undef WAITG
#undef MATH
}

extern "C" void kernel_launch(void* const* d_in, const int* in_sizes, int n_in,
                              void* d_out, int out_size, void* d_ws, size_t ws_size,
                              hipStream_t stream) {
    const float* x_init = (const float*)d_in[0];
    const float* W1     = (const float*)d_in[1];
    const float* b1     = (const float*)d_in[2];
    const float* W2     = (const float*)d_in[3];
    const float* b2     = (const float*)d_in[4];
    float* out = (float*)d_out;

    int B = in_sizes[0] / 4;
    int threads = 256;
    int blocks = (B + threads - 1) / threads;
    thermostat_kernel<<<blocks, threads, 0, stream>>>(x_init, W1, b1, W2, b2, out, B);
}